// Round 17
// baseline (163.769 us; speedup 1.0000x reference)
//
#include <hip/hip_runtime.h>

// GCN: h = mean-aggregate(feature over incoming edges, fallback feature if deg==0)
//      out = relu(h @ W^T + b)
// N=50000 nodes, E=1600000 edges, D=128.
// R17: pipeline 9 -> 5 kernels. k1 = feat2bf + p1b fused (grid-split);
//      p3c computes all partition offsets in-kernel (scan chain eliminated,
//      writes Pi[] for fillL3); aggregate unroll 8. GEMM v2 unchanged.

#define NN 50000
#define EE 1600000
#define DD 128
#define NSTRIP 3125    // 50000 / 16
#define GSB 196        // sub-buckets of 256 nodes
#define CH2 4096       // edges per wave-chunk
#define NW2 391        // ceil(EE / CH2)
#define NPBLK 98       // ceil(NW2 / 4) partition blocks
#define NFB 6250       // feat2bf blocks (NN*DD/4/256)
#define WCAP 12288     // LDS window (ints); mean need 8163

typedef __attribute__((ext_vector_type(8))) short bf16x8;
typedef __attribute__((ext_vector_type(8))) unsigned short u16x8;
typedef __attribute__((ext_vector_type(4))) float f32x4;

static __device__ __forceinline__ short f2bf(float f) {
  union { float f; unsigned u; } x; x.f = f;
  unsigned r = (x.u + 0x7FFF + ((x.u >> 16) & 1)) >> 16;
  return (short)(r & 0xFFFF);
}

// ---- k1: blocks [0,98): per-chunk 196-way counts; blocks [98,6348): f32->bf16 ----
__global__ __launch_bounds__(256) void k1(
    const int* __restrict__ dst, int* __restrict__ cnt2,
    const float* __restrict__ feature, unsigned short* __restrict__ fb) {
  if (blockIdx.x < NPBLK) {
    __shared__ int cnt[4][GSB];
    const int wv = threadIdx.x >> 6, lane = threadIdx.x & 63;
    const int w = blockIdx.x * 4 + wv;
    const bool act = (w < NW2);
    for (int i = lane; i < GSB; i += 64) cnt[wv][i] = 0;
    __syncthreads();
    if (act) {
      const int base = w * CH2;
#pragma unroll 4
      for (int it = 0; it < 16; ++it) {
        int e0 = base + it * 256 + lane * 4;
        if (e0 < EE) {
          int4 d4 = *(const int4*)(dst + e0);
          atomicAdd(&cnt[wv][((unsigned)d4.x) >> 8], 1);
          atomicAdd(&cnt[wv][((unsigned)d4.y) >> 8], 1);
          atomicAdd(&cnt[wv][((unsigned)d4.z) >> 8], 1);
          atomicAdd(&cnt[wv][((unsigned)d4.w) >> 8], 1);
        }
      }
    }
    __syncthreads();
    if (act) {
      for (int i = lane; i < GSB; i += 64) cnt2[i * NW2 + w] = cnt[wv][i];
    }
  } else {
    int i = (blockIdx.x - NPBLK) * 256 + threadIdx.x;
    if (i < NN * DD / 4) {
      float4 v = ((const float4*)feature)[i];
      short4 o;
      o.x = f2bf(v.x); o.y = f2bf(v.y); o.z = f2bf(v.z); o.w = f2bf(v.w);
      ((short4*)fb)[i] = o;
    }
  }
}

// ---- p3c: self-computed offsets (no global scan) + 196-way partition ----
// Each block scans cnt2 (300KB, L2-resident) for its 4 chunks' row-prefixes and
// the global totals; 196-elem LDS scan -> Pi; writes Pi to ws (all blocks same).
__global__ __launch_bounds__(256) void p3c(
    const int* __restrict__ src, const int* __restrict__ dst,
    const int* __restrict__ cnt2, unsigned int* __restrict__ ss,
    int* __restrict__ Pi_g) {
  __shared__ int cur[4][GSB];
  __shared__ int tarr[GSB];
  __shared__ int pw[4][GSB];
  __shared__ int wsum[4];
  const int w0 = blockIdx.x * 4;

  // per-row prefix to w0, the 4 incremental prefixes, and the row total
  for (int i = threadIdx.x; i < GSB; i += 256) {
    const int* row = cnt2 + i * NW2;
    int p = 0;
    for (int w = 0; w < w0; ++w) p += row[w];
    int p0 = p;
    int p1 = p0 + ((w0 + 0 < NW2) ? row[w0 + 0] : 0);
    int p2 = p1 + ((w0 + 1 < NW2) ? row[w0 + 1] : 0);
    int p3 = p2 + ((w0 + 2 < NW2) ? row[w0 + 2] : 0);
    int t = p3;
    for (int w = w0 + 3; w < NW2; ++w) t += row[w];
    tarr[i] = t;
    pw[0][i] = p0; pw[1][i] = p1; pw[2][i] = p2; pw[3][i] = p3;
  }
  __syncthreads();

  // exclusive scan of tarr[196] -> Pi (in tarr)
  {
    const int lane = threadIdx.x & 63;
    const int wv = threadIdx.x >> 6;
    int v = (threadIdx.x < GSB) ? tarr[threadIdx.x] : 0;
    int x = v;
#pragma unroll
    for (int d = 1; d < 64; d <<= 1) { int t = __shfl_up(x, d, 64); if (lane >= d) x += t; }
    if (lane == 63) wsum[wv] = x;
    __syncthreads();
    int pre = 0;
#pragma unroll
    for (int k = 0; k < 4; ++k) pre += (k < wv) ? wsum[k] : 0;
    if (threadIdx.x < GSB) {
      int Pi = pre + x - v;
      tarr[threadIdx.x] = Pi;
      Pi_g[threadIdx.x] = Pi;          // every block writes the same values
      if (threadIdx.x == 0) Pi_g[GSB] = EE;
    }
  }
  __syncthreads();

  for (int i = threadIdx.x; i < GSB; i += 256) {
    int Pi = tarr[i];
    cur[0][i] = Pi + pw[0][i];
    cur[1][i] = Pi + pw[1][i];
    cur[2][i] = Pi + pw[2][i];
    cur[3][i] = Pi + pw[3][i];
  }
  __syncthreads();

  // partition
  const int wv = threadIdx.x >> 6, lane = threadIdx.x & 63;
  const int w = w0 + wv;
  if (w < NW2) {
    const int base = w * CH2;
#pragma unroll 2
    for (int it = 0; it < 16; ++it) {
      int e0 = base + it * 256 + lane * 4;
      if (e0 < EE) {
        int4 s4 = *(const int4*)(src + e0);
        int4 d4 = *(const int4*)(dst + e0);
        {
          int p = atomicAdd(&cur[wv][((unsigned)d4.x) >> 8], 1);
          ss[p] = (((unsigned)d4.x) << 16) | (unsigned)s4.x;
        }
        {
          int p = atomicAdd(&cur[wv][((unsigned)d4.y) >> 8], 1);
          ss[p] = (((unsigned)d4.y) << 16) | (unsigned)s4.y;
        }
        {
          int p = atomicAdd(&cur[wv][((unsigned)d4.z) >> 8], 1);
          ss[p] = (((unsigned)d4.z) << 16) | (unsigned)s4.z;
        }
        {
          int p = atomicAdd(&cur[wv][((unsigned)d4.w) >> 8], 1);
          ss[p] = (((unsigned)d4.w) << 16) | (unsigned)s4.w;
        }
      }
    }
  }
}

// ---- fillL3: per-sub-bucket CSR build + row_start (region from Pi) ----
__global__ __launch_bounds__(1024) void fillL3(
    const unsigned int* __restrict__ ss, const int* __restrict__ Pi_g,
    int* __restrict__ csr, int* __restrict__ row_start) {
  __shared__ int win[WCAP];
  __shared__ int cur[256];
  __shared__ int rs[257];
  __shared__ int wsum2[4];
  const int g    = blockIdx.x;
  const int lo   = g * 256;
  const int nloc = (NN - lo < 256) ? (NN - lo) : 256;
  const int ebase = Pi_g[g];
  const int eend  = Pi_g[g + 1];
  const int T = eend - ebase;

  if (threadIdx.x < 256) cur[threadIdx.x] = 0;
  __syncthreads();

  for (int e = ebase + threadIdx.x; e < eend; e += 1024) {
    atomicAdd(&cur[(ss[e] >> 16) & 255], 1);
  }
  __syncthreads();

  int x = 0;
  if (threadIdx.x < 256) {
    const int lane = threadIdx.x & 63;
    x = cur[threadIdx.x];
#pragma unroll
    for (int d = 1; d < 64; d <<= 1) { int t = __shfl_up(x, d, 64); if (lane >= d) x += t; }
    if (lane == 63) wsum2[threadIdx.x >> 6] = x;
  }
  __syncthreads();
  if (threadIdx.x < 256) {
    const int wv2 = threadIdx.x >> 6;
    int pre = 0;
#pragma unroll
    for (int k = 0; k < 4; ++k) pre += (k < wv2) ? wsum2[k] : 0;
    rs[threadIdx.x + 1] = pre + x;
    if (threadIdx.x == 0) rs[0] = 0;
    cur[threadIdx.x] = 0;
  }
  __syncthreads();

  if (threadIdx.x <= nloc) row_start[lo + threadIdx.x] = ebase + rs[threadIdx.x];

  if (T <= WCAP) {
    for (int e = ebase + threadIdx.x; e < eend; e += 1024) {
      unsigned pe = ss[e];
      int li = (pe >> 16) & 255;
      int p = atomicAdd(&cur[li], 1);
      win[rs[li] + p] = (int)(pe & 0xFFFFu);
    }
    __syncthreads();
    for (int i = threadIdx.x; i < T; i += 1024) csr[ebase + i] = win[i];
  } else {
    for (int e = ebase + threadIdx.x; e < eend; e += 1024) {
      unsigned pe = ss[e];
      int li = (pe >> 16) & 255;
      int p = atomicAdd(&cur[li], 1);
      csr[ebase + rs[li] + p] = (int)(pe & 0xFFFFu);
    }
  }
}

// ---- aggregate: wave per node, 16 lanes/row, 4 edges in flight, unroll 8 ----
__global__ __launch_bounds__(256) void aggregate_bf16(
    const unsigned short* __restrict__ fb,
    const int* __restrict__ row_start,
    const int* __restrict__ csr_src,
    unsigned short* __restrict__ hb) {
  const int wave = threadIdx.x >> 6;
  const int lane = threadIdx.x & 63;
  int n = blockIdx.x * 4 + wave;
  if (n >= NN) return;

  const int start = row_start[n];
  const int end   = row_start[n + 1];
  const int deg   = end - start;
  const int q  = lane >> 4;
  const int sl = lane & 15;

  const u16x8* fp = (const u16x8*)fb;
  float acc[8];
#pragma unroll
  for (int j = 0; j < 8; ++j) acc[j] = 0.f;

#pragma unroll 8
  for (int e = start + q; e < end; e += 4) {
    int s = csr_src[e];
    u16x8 v = fp[(size_t)s * 16 + sl];
#pragma unroll
    for (int j = 0; j < 8; ++j) {
      union { unsigned u; float f; } c; c.u = ((unsigned)v[j]) << 16;
      acc[j] += c.f;
    }
  }
#pragma unroll
  for (int j = 0; j < 8; ++j) {
    acc[j] += __shfl_xor(acc[j], 16, 64);
    acc[j] += __shfl_xor(acc[j], 32, 64);
  }

  if (q == 0) {
    u16x8 hv;
    if (deg > 0) {
      float inv = 1.0f / (float)deg;
#pragma unroll
      for (int j = 0; j < 8; ++j) hv[j] = (unsigned short)f2bf(acc[j] * inv);
    } else {
      hv = fp[(size_t)n * 16 + sl];
    }
    ((u16x8*)hb)[(size_t)n * 16 + sl] = hv;
  }
}

// ---- GEMM v2: W staged in LDS as bf16 fragments; 4 waves x 2 strips/block ----
__global__ __launch_bounds__(256) void mfma_gemm2(
    const short* __restrict__ hb,
    const float* __restrict__ weight,
    const float* __restrict__ bias,
    float* __restrict__ out) {
  __shared__ bf16x8 wfrag[2048];   // 32 KB
  __shared__ float  bias_l[DD];

#pragma unroll
  for (int k = 0; k < 8; ++k) {
    int idx  = threadIdx.x * 8 + k;
    int ln   = idx & 63;
    int ct   = idx >> 6;
    int c    = ct >> 2;
    int t    = ct & 3;
    const float* wp = weight + (c * 16 + (ln & 15)) * DD + t * 32 + (ln >> 4) * 8;
    float4 w0 = *(const float4*)(wp);
    float4 w1 = *(const float4*)(wp + 4);
    bf16x8 b;
    b[0] = f2bf(w0.x); b[1] = f2bf(w0.y); b[2] = f2bf(w0.z); b[3] = f2bf(w0.w);
    b[4] = f2bf(w1.x); b[5] = f2bf(w1.y); b[6] = f2bf(w1.z); b[7] = f2bf(w1.w);
    wfrag[idx] = b;
  }
  if (threadIdx.x < DD) bias_l[threadIdx.x] = bias[threadIdx.x];
  __syncthreads();

  const int wave = threadIdx.x >> 6;
  const int lane = threadIdx.x & 63;
  const int r  = lane & 15;
  const int g  = lane >> 4;

#pragma unroll
  for (int s = 0; s < 2; ++s) {
    const int strip = blockIdx.x * 8 + wave * 2 + s;
    if (strip >= NSTRIP) continue;
    const int m0 = strip * 16;

    bf16x8 Af[4];
#pragma unroll
    for (int t = 0; t < 4; ++t) {
      Af[t] = *(const bf16x8*)(hb + (size_t)(m0 + r) * DD + t * 32 + g * 8);
    }

#pragma unroll
    for (int c = 0; c < 8; ++c) {
      f32x4 acc = {0.f, 0.f, 0.f, 0.f};
#pragma unroll
      for (int t = 0; t < 4; ++t) {
        acc = __builtin_amdgcn_mfma_f32_16x16x32_bf16(Af[t], wfrag[(c * 4 + t) * 64 + lane], acc, 0, 0, 0);
      }
      const float b = bias_l[c * 16 + r];
#pragma unroll
      for (int q = 0; q < 4; ++q) {
        int row = m0 + g * 4 + q;
        float v = acc[q] + b;
        out[(size_t)row * DD + c * 16 + r] = v > 0.f ? v : 0.f;
      }
    }
  }
}

extern "C" void kernel_launch(void* const* d_in, const int* in_sizes, int n_in,
                              void* d_out, int out_size, void* d_ws, size_t ws_size,
                              hipStream_t stream) {
  const float* feature = (const float*)d_in[0];
  const int*   src     = (const int*)d_in[1];
  const int*   dst     = (const int*)d_in[2];
  const float* weight  = (const float*)d_in[3];
  const float* bias    = (const float*)d_in[4];
  float* out = (float*)d_out;

  // ws (ints): cnt2[76636 pad 76640] Pi[197 pad 200] row_start[50001 pad 50004] | hb bf16
  int* cnt2      = (int*)d_ws;
  int* Pi_g      = cnt2 + 76640;
  int* row_start = Pi_g + 200;           // int offset 76840
  unsigned short* hb = (unsigned short*)(cnt2 + 126844);  // byte 507376, 16B aligned

  // d_out scratch (ints): ss[E] csr[E] fb(3.2M ints = 12.8MB) -- exactly 25.6MB
  unsigned int* ss = (unsigned int*)d_out;
  int* csr = (int*)d_out + EE;
  unsigned short* fb = (unsigned short*)((int*)d_out + 2 * EE);

  k1<<<NPBLK + NFB, 256, 0, stream>>>(dst, cnt2, feature, fb);
  p3c<<<NPBLK, 256, 0, stream>>>(src, dst, cnt2, ss, Pi_g);
  fillL3<<<GSB, 1024, 0, stream>>>(ss, Pi_g, csr, row_start);
  aggregate_bf16<<<(NN + 3) / 4, 256, 0, stream>>>(fb, row_start, csr, hb);
  mfma_gemm2<<<(NSTRIP + 7) / 8, 256, 0, stream>>>((const short*)hb, weight, bias, out);
}

// Round 19
// 123.338 us; speedup vs baseline: 1.3278x; 1.3278x over previous
//
#include <hip/hip_runtime.h>

// GCN: h = mean-aggregate(feature over incoming edges, fallback feature if deg==0)
//      out = relu(h @ W^T + b)
// N=50000 nodes, E=1600000 edges, D=128.
// R20 == R18 resubmit (infra failure): revert R17's p3c (serial-prologue
// regression) to the measured R16 scan chain (sA/p2/sC) + p3b. Keep k1 fusion
// (feat2bf+p1b) and aggregate unroll 8. GEMM v2 unchanged.

#define NN 50000
#define EE 1600000
#define DD 128
#define NSTRIP 3125    // 50000 / 16
#define GSB 196        // sub-buckets of 256 nodes
#define CH2 4096       // edges per wave-chunk
#define NW2 391        // ceil(EE / CH2)
#define NPBLK 98       // ceil(NW2 / 4) partition blocks
#define NFB 6250       // feat2bf blocks (NN*DD/4/256)
#define NCNT (GSB * NW2)   // 76636
#define NSA 75         // ceil(NCNT / 1024)
#define WCAP 12288     // LDS window (ints); mean need 8163

typedef __attribute__((ext_vector_type(8))) short bf16x8;
typedef __attribute__((ext_vector_type(8))) unsigned short u16x8;
typedef __attribute__((ext_vector_type(4))) float f32x4;

static __device__ __forceinline__ short f2bf(float f) {
  union { float f; unsigned u; } x; x.f = f;
  unsigned r = (x.u + 0x7FFF + ((x.u >> 16) & 1)) >> 16;
  return (short)(r & 0xFFFF);
}

// ---- k1: blocks [0,98): per-chunk 196-way counts; blocks [98,6348): f32->bf16 ----
__global__ __launch_bounds__(256) void k1(
    const int* __restrict__ dst, int* __restrict__ cnt2,
    const float* __restrict__ feature, unsigned short* __restrict__ fb) {
  if (blockIdx.x < NPBLK) {
    __shared__ int cnt[4][GSB];
    const int wv = threadIdx.x >> 6, lane = threadIdx.x & 63;
    const int w = blockIdx.x * 4 + wv;
    const bool act = (w < NW2);
    for (int i = lane; i < GSB; i += 64) cnt[wv][i] = 0;
    __syncthreads();
    if (act) {
      const int base = w * CH2;
#pragma unroll 4
      for (int it = 0; it < 16; ++it) {
        int e0 = base + it * 256 + lane * 4;
        if (e0 < EE) {
          int4 d4 = *(const int4*)(dst + e0);
          atomicAdd(&cnt[wv][((unsigned)d4.x) >> 8], 1);
          atomicAdd(&cnt[wv][((unsigned)d4.y) >> 8], 1);
          atomicAdd(&cnt[wv][((unsigned)d4.z) >> 8], 1);
          atomicAdd(&cnt[wv][((unsigned)d4.w) >> 8], 1);
        }
      }
    }
    __syncthreads();
    if (act) {
      for (int i = lane; i < GSB; i += 64) cnt2[i * NW2 + w] = cnt[wv][i];
    }
  } else {
    int i = (blockIdx.x - NPBLK) * 256 + threadIdx.x;
    if (i < NN * DD / 4) {
      float4 v = ((const float4*)feature)[i];
      short4 o;
      o.x = f2bf(v.x); o.y = f2bf(v.y); o.z = f2bf(v.z); o.w = f2bf(v.w);
      ((short4*)fb)[i] = o;
    }
  }
}

// ---- sA: per-block sums of cnt2 ----
__global__ __launch_bounds__(1024) void sA_bsum(
    const int* __restrict__ in, int* __restrict__ bsum, int n) {
  __shared__ int ws[16];
  int i = blockIdx.x * 1024 + threadIdx.x;
  int v = (i < n) ? in[i] : 0;
#pragma unroll
  for (int d = 1; d < 64; d <<= 1) v += __shfl_xor(v, d, 64);
  int wv = threadIdx.x >> 6, lane = threadIdx.x & 63;
  if (lane == 0) ws[wv] = v;
  __syncthreads();
  if (threadIdx.x == 0) {
    int s = 0;
#pragma unroll
    for (int k = 0; k < 16; ++k) s += ws[k];
    bsum[blockIdx.x] = s;
  }
}

// ---- generic single-block exclusive scan (in-place safe) ----
__global__ __launch_bounds__(1024) void p2_scan(
    const int* __restrict__ in, int* __restrict__ out, int n) {
  __shared__ int ws[16];
  __shared__ int s_off;
  const int wv = threadIdx.x >> 6, lane = threadIdx.x & 63;
  if (threadIdx.x == 0) s_off = 0;
  __syncthreads();
  for (int base = 0; base < n; base += 1024) {
    int i = base + threadIdx.x;
    int v = (i < n) ? in[i] : 0;
    int x = v;
#pragma unroll
    for (int d = 1; d < 64; d <<= 1) { int t = __shfl_up(x, d, 64); if (lane >= d) x += t; }
    if (lane == 63) ws[wv] = x;
    __syncthreads();
    if (threadIdx.x < 16) {
      int w = ws[threadIdx.x];
#pragma unroll
      for (int d = 1; d < 16; d <<= 1) { int t = __shfl_up(w, d, 16); if (threadIdx.x >= d) w += t; }
      ws[threadIdx.x] = w;
    }
    __syncthreads();
    int off = s_off + ((wv == 0) ? 0 : ws[wv - 1]);
    if (i < n) out[i] = off + x - v;
    __syncthreads();
    if (threadIdx.x == 0) s_off += ws[15];
    __syncthreads();
  }
}

// ---- sC: apply block offsets (exclusive scan finalize, in-place) ----
__global__ __launch_bounds__(1024) void sC_apply(
    int* __restrict__ data, const int* __restrict__ bsum, int n) {
  __shared__ int ws[16];
  int i = blockIdx.x * 1024 + threadIdx.x;
  int wv = threadIdx.x >> 6, lane = threadIdx.x & 63;
  int v = (i < n) ? data[i] : 0;
  int x = v;
#pragma unroll
  for (int d = 1; d < 64; d <<= 1) { int t = __shfl_up(x, d, 64); if (lane >= d) x += t; }
  if (lane == 63) ws[wv] = x;
  __syncthreads();
  if (threadIdx.x < 16) {
    int w = ws[threadIdx.x];
#pragma unroll
    for (int d = 1; d < 16; d <<= 1) { int t = __shfl_up(w, d, 16); if (threadIdx.x >= d) w += t; }
    ws[threadIdx.x] = w;
  }
  __syncthreads();
  int off = bsum[blockIdx.x] + ((wv == 0) ? 0 : ws[wv - 1]);
  if (i < n) data[i] = off + x - v;
}

// ---- p3b: 196-way partition of packed edges (per-wave LDS cursors) ----
__global__ __launch_bounds__(256) void p3b(
    const int* __restrict__ src, const int* __restrict__ dst,
    const int* __restrict__ off2, unsigned int* __restrict__ ss) {
  __shared__ int cur[4][GSB];
  const int wv = threadIdx.x >> 6, lane = threadIdx.x & 63;
  const int w = blockIdx.x * 4 + wv;
  const bool act = (w < NW2);
  if (act) {
    for (int i = lane; i < GSB; i += 64) cur[wv][i] = off2[i * NW2 + w];
  }
  __syncthreads();
  if (act) {
    const int base = w * CH2;
#pragma unroll 2
    for (int it = 0; it < 16; ++it) {
      int e0 = base + it * 256 + lane * 4;
      if (e0 < EE) {
        int4 s4 = *(const int4*)(src + e0);
        int4 d4 = *(const int4*)(dst + e0);
        {
          int p = atomicAdd(&cur[wv][((unsigned)d4.x) >> 8], 1);
          ss[p] = (((unsigned)d4.x) << 16) | (unsigned)s4.x;
        }
        {
          int p = atomicAdd(&cur[wv][((unsigned)d4.y) >> 8], 1);
          ss[p] = (((unsigned)d4.y) << 16) | (unsigned)s4.y;
        }
        {
          int p = atomicAdd(&cur[wv][((unsigned)d4.z) >> 8], 1);
          ss[p] = (((unsigned)d4.z) << 16) | (unsigned)s4.z;
        }
        {
          int p = atomicAdd(&cur[wv][((unsigned)d4.w) >> 8], 1);
          ss[p] = (((unsigned)d4.w) << 16) | (unsigned)s4.w;
        }
      }
    }
  }
}

// ---- fillL2: per-sub-bucket CSR build + row_start (reads ONLY own region) ----
__global__ __launch_bounds__(1024) void fillL2(
    const unsigned int* __restrict__ ss, const int* __restrict__ off2,
    int* __restrict__ csr, int* __restrict__ row_start) {
  __shared__ int win[WCAP];
  __shared__ int cur[256];
  __shared__ int rs[257];
  __shared__ int wsum2[4];
  const int g    = blockIdx.x;
  const int lo   = g * 256;
  const int nloc = (NN - lo < 256) ? (NN - lo) : 256;
  const int ebase = off2[g * NW2];
  const int eend  = (g < GSB - 1) ? off2[(g + 1) * NW2] : EE;
  const int T = eend - ebase;

  if (threadIdx.x < 256) cur[threadIdx.x] = 0;
  __syncthreads();

  for (int e = ebase + threadIdx.x; e < eend; e += 1024) {
    atomicAdd(&cur[(ss[e] >> 16) & 255], 1);
  }
  __syncthreads();

  int x = 0;
  if (threadIdx.x < 256) {
    const int lane = threadIdx.x & 63;
    x = cur[threadIdx.x];
#pragma unroll
    for (int d = 1; d < 64; d <<= 1) { int t = __shfl_up(x, d, 64); if (lane >= d) x += t; }
    if (lane == 63) wsum2[threadIdx.x >> 6] = x;
  }
  __syncthreads();
  if (threadIdx.x < 256) {
    const int wv2 = threadIdx.x >> 6;
    int pre = 0;
#pragma unroll
    for (int k = 0; k < 4; ++k) pre += (k < wv2) ? wsum2[k] : 0;
    rs[threadIdx.x + 1] = pre + x;
    if (threadIdx.x == 0) rs[0] = 0;
    cur[threadIdx.x] = 0;
  }
  __syncthreads();

  if (threadIdx.x <= nloc) row_start[lo + threadIdx.x] = ebase + rs[threadIdx.x];

  if (T <= WCAP) {
    for (int e = ebase + threadIdx.x; e < eend; e += 1024) {
      unsigned pe = ss[e];
      int li = (pe >> 16) & 255;
      int p = atomicAdd(&cur[li], 1);
      win[rs[li] + p] = (int)(pe & 0xFFFFu);
    }
    __syncthreads();
    for (int i = threadIdx.x; i < T; i += 1024) csr[ebase + i] = win[i];
  } else {
    for (int e = ebase + threadIdx.x; e < eend; e += 1024) {
      unsigned pe = ss[e];
      int li = (pe >> 16) & 255;
      int p = atomicAdd(&cur[li], 1);
      csr[ebase + rs[li] + p] = (int)(pe & 0xFFFFu);
    }
  }
}

// ---- aggregate: wave per node, 16 lanes/row, 4 edges in flight, unroll 8 ----
__global__ __launch_bounds__(256) void aggregate_bf16(
    const unsigned short* __restrict__ fb,
    const int* __restrict__ row_start,
    const int* __restrict__ csr_src,
    unsigned short* __restrict__ hb) {
  const int wave = threadIdx.x >> 6;
  const int lane = threadIdx.x & 63;
  int n = blockIdx.x * 4 + wave;
  if (n >= NN) return;

  const int start = row_start[n];
  const int end   = row_start[n + 1];
  const int deg   = end - start;
  const int q  = lane >> 4;
  const int sl = lane & 15;

  const u16x8* fp = (const u16x8*)fb;
  float acc[8];
#pragma unroll
  for (int j = 0; j < 8; ++j) acc[j] = 0.f;

#pragma unroll 8
  for (int e = start + q; e < end; e += 4) {
    int s = csr_src[e];
    u16x8 v = fp[(size_t)s * 16 + sl];
#pragma unroll
    for (int j = 0; j < 8; ++j) {
      union { unsigned u; float f; } c; c.u = ((unsigned)v[j]) << 16;
      acc[j] += c.f;
    }
  }
#pragma unroll
  for (int j = 0; j < 8; ++j) {
    acc[j] += __shfl_xor(acc[j], 16, 64);
    acc[j] += __shfl_xor(acc[j], 32, 64);
  }

  if (q == 0) {
    u16x8 hv;
    if (deg > 0) {
      float inv = 1.0f / (float)deg;
#pragma unroll
      for (int j = 0; j < 8; ++j) hv[j] = (unsigned short)f2bf(acc[j] * inv);
    } else {
      hv = fp[(size_t)n * 16 + sl];
    }
    ((u16x8*)hb)[(size_t)n * 16 + sl] = hv;
  }
}

// ---- GEMM v2: W staged in LDS as bf16 fragments; 4 waves x 2 strips/block ----
__global__ __launch_bounds__(256) void mfma_gemm2(
    const short* __restrict__ hb,
    const float* __restrict__ weight,
    const float* __restrict__ bias,
    float* __restrict__ out) {
  __shared__ bf16x8 wfrag[2048];   // 32 KB
  __shared__ float  bias_l[DD];

#pragma unroll
  for (int k = 0; k < 8; ++k) {
    int idx  = threadIdx.x * 8 + k;
    int ln   = idx & 63;
    int ct   = idx >> 6;
    int c    = ct >> 2;
    int t    = ct & 3;
    const float* wp = weight + (c * 16 + (ln & 15)) * DD + t * 32 + (ln >> 4) * 8;
    float4 w0 = *(const float4*)(wp);
    float4 w1 = *(const float4*)(wp + 4);
    bf16x8 b;
    b[0] = f2bf(w0.x); b[1] = f2bf(w0.y); b[2] = f2bf(w0.z); b[3] = f2bf(w0.w);
    b[4] = f2bf(w1.x); b[5] = f2bf(w1.y); b[6] = f2bf(w1.z); b[7] = f2bf(w1.w);
    wfrag[idx] = b;
  }
  if (threadIdx.x < DD) bias_l[threadIdx.x] = bias[threadIdx.x];
  __syncthreads();

  const int wave = threadIdx.x >> 6;
  const int lane = threadIdx.x & 63;
  const int r  = lane & 15;
  const int g  = lane >> 4;

#pragma unroll
  for (int s = 0; s < 2; ++s) {
    const int strip = blockIdx.x * 8 + wave * 2 + s;
    if (strip >= NSTRIP) continue;
    const int m0 = strip * 16;

    bf16x8 Af[4];
#pragma unroll
    for (int t = 0; t < 4; ++t) {
      Af[t] = *(const bf16x8*)(hb + (size_t)(m0 + r) * DD + t * 32 + g * 8);
    }

#pragma unroll
    for (int c = 0; c < 8; ++c) {
      f32x4 acc = {0.f, 0.f, 0.f, 0.f};
#pragma unroll
      for (int t = 0; t < 4; ++t) {
        acc = __builtin_amdgcn_mfma_f32_16x16x32_bf16(Af[t], wfrag[(c * 4 + t) * 64 + lane], acc, 0, 0, 0);
      }
      const float b = bias_l[c * 16 + r];
#pragma unroll
      for (int q = 0; q < 4; ++q) {
        int row = m0 + g * 4 + q;
        float v = acc[q] + b;
        out[(size_t)row * DD + c * 16 + r] = v > 0.f ? v : 0.f;
      }
    }
  }
}

extern "C" void kernel_launch(void* const* d_in, const int* in_sizes, int n_in,
                              void* d_out, int out_size, void* d_ws, size_t ws_size,
                              hipStream_t stream) {
  const float* feature = (const float*)d_in[0];
  const int*   src     = (const int*)d_in[1];
  const int*   dst     = (const int*)d_in[2];
  const float* weight  = (const float*)d_in[3];
  const float* bias    = (const float*)d_in[4];
  float* out = (float*)d_out;

  // ws (ints): cnt2[76636 pad 76640] bsum[80] row_start[50001 pad 50004] | hb bf16
  int* cnt2      = (int*)d_ws;
  int* bsum      = cnt2 + 76640;
  int* row_start = bsum + 80;
  unsigned short* hb = (unsigned short*)(cnt2 + 126724);  // byte 506896, 16B aligned

  // d_out scratch (ints): ss[E] csr[E] fb(3.2M ints = 12.8MB) -- exactly 25.6MB
  unsigned int* ss = (unsigned int*)d_out;
  int* csr = (int*)d_out + EE;
  unsigned short* fb = (unsigned short*)((int*)d_out + 2 * EE);

  k1<<<NPBLK + NFB, 256, 0, stream>>>(dst, cnt2, feature, fb);
  sA_bsum<<<NSA, 1024, 0, stream>>>(cnt2, bsum, NCNT);
  p2_scan<<<1, 1024, 0, stream>>>(bsum, bsum, NSA);
  sC_apply<<<NSA, 1024, 0, stream>>>(cnt2, bsum, NCNT);
  p3b<<<NPBLK, 256, 0, stream>>>(src, dst, cnt2, ss);
  fillL2<<<GSB, 1024, 0, stream>>>(ss, cnt2, csr, row_start);
  aggregate_bf16<<<(NN + 3) / 4, 256, 0, stream>>>(fb, row_start, csr, hb);
  mfma_gemm2<<<(NSTRIP + 7) / 8, 256, 0, stream>>>((const short*)hb, weight, bias, out);
}

// Round 20
// 108.385 us; speedup vs baseline: 1.5110x; 1.1380x over previous
//
#include <hip/hip_runtime.h>

// GCN: h = mean-aggregate(feature over incoming edges, fallback feature if deg==0)
//      out = relu(h @ W^T + b)
// N=50000 nodes, E=1600000 edges, D=128.
// R21: revert aggregate inner loop to R16's unroll-4 (R19's unroll-8 cost
//      occupancy 63->38%, +16us); fuse fillL2+aggregate into fillagg (gather
//      src ids from the LDS window; csr/row_start globals eliminated).
//      2 blocks per sub-bucket keep ~24 waves/CU for the gather.

#define NN 50000
#define EE 1600000
#define DD 128
#define NSTRIP 3125    // 50000 / 16
#define GSB 196        // sub-buckets of 256 nodes
#define CH2 4096       // edges per wave-chunk
#define NW2 391        // ceil(EE / CH2)
#define NPBLK 98       // ceil(NW2 / 4) partition blocks
#define NFB 6250       // feat2bf blocks (NN*DD/4/256)
#define NCNT (GSB * NW2)   // 76636
#define NSA 75         // ceil(NCNT / 1024)
#define WCAPH 8192     // per-half LDS window (ints); mean need ~4082

typedef __attribute__((ext_vector_type(8))) short bf16x8;
typedef __attribute__((ext_vector_type(8))) unsigned short u16x8;
typedef __attribute__((ext_vector_type(4))) float f32x4;

static __device__ __forceinline__ short f2bf(float f) {
  union { float f; unsigned u; } x; x.f = f;
  unsigned r = (x.u + 0x7FFF + ((x.u >> 16) & 1)) >> 16;
  return (short)(r & 0xFFFF);
}

// ---- k1: blocks [0,98): per-chunk 196-way counts; blocks [98,6348): f32->bf16 ----
__global__ __launch_bounds__(256) void k1(
    const int* __restrict__ dst, int* __restrict__ cnt2,
    const float* __restrict__ feature, unsigned short* __restrict__ fb) {
  if (blockIdx.x < NPBLK) {
    __shared__ int cnt[4][GSB];
    const int wv = threadIdx.x >> 6, lane = threadIdx.x & 63;
    const int w = blockIdx.x * 4 + wv;
    const bool act = (w < NW2);
    for (int i = lane; i < GSB; i += 64) cnt[wv][i] = 0;
    __syncthreads();
    if (act) {
      const int base = w * CH2;
#pragma unroll 4
      for (int it = 0; it < 16; ++it) {
        int e0 = base + it * 256 + lane * 4;
        if (e0 < EE) {
          int4 d4 = *(const int4*)(dst + e0);
          atomicAdd(&cnt[wv][((unsigned)d4.x) >> 8], 1);
          atomicAdd(&cnt[wv][((unsigned)d4.y) >> 8], 1);
          atomicAdd(&cnt[wv][((unsigned)d4.z) >> 8], 1);
          atomicAdd(&cnt[wv][((unsigned)d4.w) >> 8], 1);
        }
      }
    }
    __syncthreads();
    if (act) {
      for (int i = lane; i < GSB; i += 64) cnt2[i * NW2 + w] = cnt[wv][i];
    }
  } else {
    int i = (blockIdx.x - NPBLK) * 256 + threadIdx.x;
    if (i < NN * DD / 4) {
      float4 v = ((const float4*)feature)[i];
      short4 o;
      o.x = f2bf(v.x); o.y = f2bf(v.y); o.z = f2bf(v.z); o.w = f2bf(v.w);
      ((short4*)fb)[i] = o;
    }
  }
}

// ---- sA: per-block sums of cnt2 ----
__global__ __launch_bounds__(1024) void sA_bsum(
    const int* __restrict__ in, int* __restrict__ bsum, int n) {
  __shared__ int ws[16];
  int i = blockIdx.x * 1024 + threadIdx.x;
  int v = (i < n) ? in[i] : 0;
#pragma unroll
  for (int d = 1; d < 64; d <<= 1) v += __shfl_xor(v, d, 64);
  int wv = threadIdx.x >> 6, lane = threadIdx.x & 63;
  if (lane == 0) ws[wv] = v;
  __syncthreads();
  if (threadIdx.x == 0) {
    int s = 0;
#pragma unroll
    for (int k = 0; k < 16; ++k) s += ws[k];
    bsum[blockIdx.x] = s;
  }
}

// ---- generic single-block exclusive scan (in-place safe) ----
__global__ __launch_bounds__(1024) void p2_scan(
    const int* __restrict__ in, int* __restrict__ out, int n) {
  __shared__ int ws[16];
  __shared__ int s_off;
  const int wv = threadIdx.x >> 6, lane = threadIdx.x & 63;
  if (threadIdx.x == 0) s_off = 0;
  __syncthreads();
  for (int base = 0; base < n; base += 1024) {
    int i = base + threadIdx.x;
    int v = (i < n) ? in[i] : 0;
    int x = v;
#pragma unroll
    for (int d = 1; d < 64; d <<= 1) { int t = __shfl_up(x, d, 64); if (lane >= d) x += t; }
    if (lane == 63) ws[wv] = x;
    __syncthreads();
    if (threadIdx.x < 16) {
      int w = ws[threadIdx.x];
#pragma unroll
      for (int d = 1; d < 16; d <<= 1) { int t = __shfl_up(w, d, 16); if (threadIdx.x >= d) w += t; }
      ws[threadIdx.x] = w;
    }
    __syncthreads();
    int off = s_off + ((wv == 0) ? 0 : ws[wv - 1]);
    if (i < n) out[i] = off + x - v;
    __syncthreads();
    if (threadIdx.x == 0) s_off += ws[15];
    __syncthreads();
  }
}

// ---- sC: apply block offsets (exclusive scan finalize, in-place) ----
__global__ __launch_bounds__(1024) void sC_apply(
    int* __restrict__ data, const int* __restrict__ bsum, int n) {
  __shared__ int ws[16];
  int i = blockIdx.x * 1024 + threadIdx.x;
  int wv = threadIdx.x >> 6, lane = threadIdx.x & 63;
  int v = (i < n) ? data[i] : 0;
  int x = v;
#pragma unroll
  for (int d = 1; d < 64; d <<= 1) { int t = __shfl_up(x, d, 64); if (lane >= d) x += t; }
  if (lane == 63) ws[wv] = x;
  __syncthreads();
  if (threadIdx.x < 16) {
    int w = ws[threadIdx.x];
#pragma unroll
    for (int d = 1; d < 16; d <<= 1) { int t = __shfl_up(w, d, 16); if (threadIdx.x >= d) w += t; }
    ws[threadIdx.x] = w;
  }
  __syncthreads();
  int off = bsum[blockIdx.x] + ((wv == 0) ? 0 : ws[wv - 1]);
  if (i < n) data[i] = off + x - v;
}

// ---- p3b: 196-way partition of packed edges (per-wave LDS cursors) ----
__global__ __launch_bounds__(256) void p3b(
    const int* __restrict__ src, const int* __restrict__ dst,
    const int* __restrict__ off2, unsigned int* __restrict__ ss) {
  __shared__ int cur[4][GSB];
  const int wv = threadIdx.x >> 6, lane = threadIdx.x & 63;
  const int w = blockIdx.x * 4 + wv;
  const bool act = (w < NW2);
  if (act) {
    for (int i = lane; i < GSB; i += 64) cur[wv][i] = off2[i * NW2 + w];
  }
  __syncthreads();
  if (act) {
    const int base = w * CH2;
#pragma unroll 2
    for (int it = 0; it < 16; ++it) {
      int e0 = base + it * 256 + lane * 4;
      if (e0 < EE) {
        int4 s4 = *(const int4*)(src + e0);
        int4 d4 = *(const int4*)(dst + e0);
        {
          int p = atomicAdd(&cur[wv][((unsigned)d4.x) >> 8], 1);
          ss[p] = (((unsigned)d4.x) << 16) | (unsigned)s4.x;
        }
        {
          int p = atomicAdd(&cur[wv][((unsigned)d4.y) >> 8], 1);
          ss[p] = (((unsigned)d4.y) << 16) | (unsigned)s4.y;
        }
        {
          int p = atomicAdd(&cur[wv][((unsigned)d4.z) >> 8], 1);
          ss[p] = (((unsigned)d4.z) << 16) | (unsigned)s4.z;
        }
        {
          int p = atomicAdd(&cur[wv][((unsigned)d4.w) >> 8], 1);
          ss[p] = (((unsigned)d4.w) << 16) | (unsigned)s4.w;
        }
      }
    }
  }
}

// ---- fillagg: fused CSR-window build + mean-aggregate ----
// 2 blocks per sub-bucket (half = 128 nodes each). Window lives in LDS only;
// aggregate gathers src ids from LDS. csr_fb is a global fallback region,
// touched only if a half-window exceeds WCAPH (statistically unreachable).
__global__ __launch_bounds__(1024) void fillagg(
    const unsigned int* __restrict__ ss, const int* __restrict__ off2,
    const unsigned short* __restrict__ fb,
    int* __restrict__ csr_fb,
    unsigned short* __restrict__ hb) {
  __shared__ int win[WCAPH];
  __shared__ int cur[256];
  __shared__ int rs[257];
  __shared__ int wsum2[4];
  const int g    = blockIdx.x >> 1;
  const int half = blockIdx.x & 1;
  const int lo   = g * 256;
  const int nl_all = (NN - lo < 256) ? (NN - lo) : 256;
  int h0 = half * 128;
  int h1 = h0 + 128;
  if (h1 > nl_all) h1 = nl_all;
  if (h1 < h0) h1 = h0;
  const int ebase = off2[g * NW2];
  const int eend  = (g < GSB - 1) ? off2[(g + 1) * NW2] : EE;

  // pass 1: per-node degree counts over the whole sub-bucket region
  if (threadIdx.x < 256) cur[threadIdx.x] = 0;
  __syncthreads();
  for (int e = ebase + threadIdx.x; e < eend; e += 1024) {
    atomicAdd(&cur[(ss[e] >> 16) & 255], 1);
  }
  __syncthreads();

  // scan cur[256] -> rs[0..256] (region-local offsets)
  int x = 0;
  if (threadIdx.x < 256) {
    const int lane = threadIdx.x & 63;
    x = cur[threadIdx.x];
#pragma unroll
    for (int d = 1; d < 64; d <<= 1) { int t = __shfl_up(x, d, 64); if (lane >= d) x += t; }
    if (lane == 63) wsum2[threadIdx.x >> 6] = x;
  }
  __syncthreads();
  if (threadIdx.x < 256) {
    const int wv2 = threadIdx.x >> 6;
    int pre = 0;
#pragma unroll
    for (int k = 0; k < 4; ++k) pre += (k < wv2) ? wsum2[k] : 0;
    rs[threadIdx.x + 1] = pre + x;
    if (threadIdx.x == 0) rs[0] = 0;
    cur[threadIdx.x] = 0;   // re-zero for placement pass
  }
  __syncthreads();

  const int wb = rs[h0];
  const int Th = rs[h1] - wb;
  const bool inlds = (Th <= WCAPH);

  // pass 2: place this half's edges into the LDS window (or global fallback)
  for (int e = ebase + threadIdx.x; e < eend; e += 1024) {
    unsigned pe = ss[e];
    int li = (pe >> 16) & 255;
    if (li >= h0 && li < h1) {
      int p = atomicAdd(&cur[li], 1);
      if (inlds) win[rs[li] - wb + p] = (int)(pe & 0xFFFFu);
      else       csr_fb[ebase + rs[li] + p] = (int)(pe & 0xFFFFu);
    }
  }
  __syncthreads();

  // phase B: aggregate this half's nodes (R16 loop shape: 16 lanes/row,
  // 4 edges in flight, unroll 4 -- low VGPR, occupancy-friendly)
  const int wv = threadIdx.x >> 6;
  const int lane = threadIdx.x & 63;
  const int q  = lane >> 4;
  const int sl = lane & 15;
  const u16x8* fp = (const u16x8*)fb;

  for (int ln = h0 + wv; ln < h1; ln += 16) {
    const int st = rs[ln];
    const int en = rs[ln + 1];
    const int deg = en - st;
    const int n = lo + ln;

    float acc[8];
#pragma unroll
    for (int j = 0; j < 8; ++j) acc[j] = 0.f;

#pragma unroll 4
    for (int e = st + q; e < en; e += 4) {
      int s = inlds ? win[e - wb] : csr_fb[ebase + e];
      u16x8 v = fp[(size_t)s * 16 + sl];
#pragma unroll
      for (int j = 0; j < 8; ++j) {
        union { unsigned u; float f; } c; c.u = ((unsigned)v[j]) << 16;
        acc[j] += c.f;
      }
    }
#pragma unroll
    for (int j = 0; j < 8; ++j) {
      acc[j] += __shfl_xor(acc[j], 16, 64);
      acc[j] += __shfl_xor(acc[j], 32, 64);
    }

    if (q == 0) {
      u16x8 hv;
      if (deg > 0) {
        float inv = 1.0f / (float)deg;
#pragma unroll
        for (int j = 0; j < 8; ++j) hv[j] = (unsigned short)f2bf(acc[j] * inv);
      } else {
        hv = fp[(size_t)n * 16 + sl];
      }
      ((u16x8*)hb)[(size_t)n * 16 + sl] = hv;
    }
  }
}

// ---- GEMM v2: W staged in LDS as bf16 fragments; 4 waves x 2 strips/block ----
__global__ __launch_bounds__(256) void mfma_gemm2(
    const short* __restrict__ hb,
    const float* __restrict__ weight,
    const float* __restrict__ bias,
    float* __restrict__ out) {
  __shared__ bf16x8 wfrag[2048];   // 32 KB
  __shared__ float  bias_l[DD];

#pragma unroll
  for (int k = 0; k < 8; ++k) {
    int idx  = threadIdx.x * 8 + k;
    int ln   = idx & 63;
    int ct   = idx >> 6;
    int c    = ct >> 2;
    int t    = ct & 3;
    const float* wp = weight + (c * 16 + (ln & 15)) * DD + t * 32 + (ln >> 4) * 8;
    float4 w0 = *(const float4*)(wp);
    float4 w1 = *(const float4*)(wp + 4);
    bf16x8 b;
    b[0] = f2bf(w0.x); b[1] = f2bf(w0.y); b[2] = f2bf(w0.z); b[3] = f2bf(w0.w);
    b[4] = f2bf(w1.x); b[5] = f2bf(w1.y); b[6] = f2bf(w1.z); b[7] = f2bf(w1.w);
    wfrag[idx] = b;
  }
  if (threadIdx.x < DD) bias_l[threadIdx.x] = bias[threadIdx.x];
  __syncthreads();

  const int wave = threadIdx.x >> 6;
  const int lane = threadIdx.x & 63;
  const int r  = lane & 15;
  const int g  = lane >> 4;

#pragma unroll
  for (int s = 0; s < 2; ++s) {
    const int strip = blockIdx.x * 8 + wave * 2 + s;
    if (strip >= NSTRIP) continue;
    const int m0 = strip * 16;

    bf16x8 Af[4];
#pragma unroll
    for (int t = 0; t < 4; ++t) {
      Af[t] = *(const bf16x8*)(hb + (size_t)(m0 + r) * DD + t * 32 + g * 8);
    }

#pragma unroll
    for (int c = 0; c < 8; ++c) {
      f32x4 acc = {0.f, 0.f, 0.f, 0.f};
#pragma unroll
      for (int t = 0; t < 4; ++t) {
        acc = __builtin_amdgcn_mfma_f32_16x16x32_bf16(Af[t], wfrag[(c * 4 + t) * 64 + lane], acc, 0, 0, 0);
      }
      const float b = bias_l[c * 16 + r];
#pragma unroll
      for (int q = 0; q < 4; ++q) {
        int row = m0 + g * 4 + q;
        float v = acc[q] + b;
        out[(size_t)row * DD + c * 16 + r] = v > 0.f ? v : 0.f;
      }
    }
  }
}

extern "C" void kernel_launch(void* const* d_in, const int* in_sizes, int n_in,
                              void* d_out, int out_size, void* d_ws, size_t ws_size,
                              hipStream_t stream) {
  const float* feature = (const float*)d_in[0];
  const int*   src     = (const int*)d_in[1];
  const int*   dst     = (const int*)d_in[2];
  const float* weight  = (const float*)d_in[3];
  const float* bias    = (const float*)d_in[4];
  float* out = (float*)d_out;

  // ws (ints): cnt2[76636 pad 76640] bsum[80] | hb bf16 (12.8MB)
  int* cnt2 = (int*)d_ws;
  int* bsum = cnt2 + 76640;
  unsigned short* hb = (unsigned short*)(cnt2 + 126724);  // byte 506896, 16B aligned

  // d_out scratch (ints): ss[E] csr_fb[E] fb(3.2M ints = 12.8MB) -- 25.6MB
  unsigned int* ss = (unsigned int*)d_out;
  int* csr_fb = (int*)d_out + EE;
  unsigned short* fb = (unsigned short*)((int*)d_out + 2 * EE);

  k1<<<NPBLK + NFB, 256, 0, stream>>>(dst, cnt2, feature, fb);
  sA_bsum<<<NSA, 1024, 0, stream>>>(cnt2, bsum, NCNT);
  p2_scan<<<1, 1024, 0, stream>>>(bsum, bsum, NSA);
  sC_apply<<<NSA, 1024, 0, stream>>>(cnt2, bsum, NCNT);
  p3b<<<NPBLK, 256, 0, stream>>>(src, dst, cnt2, ss);
  fillagg<<<GSB * 2, 1024, 0, stream>>>(ss, cnt2, fb, csr_fb, hb);
  mfma_gemm2<<<(NSTRIP + 7) / 8, 256, 0, stream>>>((const short*)hb, weight, bias, out);
}